// Round 1
// 178.014 us; speedup vs baseline: 1.0520x; 1.0520x over previous
//
#include <hip/hip_runtime.h>
#include <stdint.h>

// Mimic numpy (no FMA contraction) for all math feeding discrete decisions.
#pragma clang fp contract(off)

#define BS 32
#define NANCH 90000
#define KEEP_PRE 1000
#define KEEP_POST 300
#define NMS_THR 0.7f
#define NBINS 4096      // top-12-bit histogram of monotone float bits
#define HREP 4129       // NBINS + 33 pad: copy1 lands on shifted banks
#define CAND_MAX 4096
#define MW 16           // u64 mask words per NMS row (16*64 = 1024 >= 1000)
#define CNT_STRIDE 32   // u32s between per-image counters (128 B = 1 cacheline)
#define NSLICE 8        // select_kernel: i-slices per image (CU spreading)
#define NF4 22500       // NANCH / 4 float4s per image

typedef unsigned long long u64;
typedef unsigned int u32;

// ---- workspace layout (bytes); nothing needs pre-zeroing ----
#define CNT_OFF    0                                        // u32[BS*CNT_STRIDE]
#define CNT_BYTES  ((size_t)BS * CNT_STRIDE * 4)            // 4096
#define CAND_OFF   (CNT_OFF + CNT_BYTES)                    // u64[BS][CAND_MAX]
#define BOX_OFF    (CAND_OFF + (size_t)BS * CAND_MAX * 8)   // float4[BS][KEEP_PRE]
#define SCORE_OFF  (BOX_OFF + (size_t)BS * KEEP_PRE * 16)   // float[BS][KEEP_PRE]
#define MASK_OFF   (SCORE_OFF + (size_t)BS * KEEP_PRE * 4)  // u64[BS][KEEP_PRE][MW]
// total ~5.8 MB

__device__ __forceinline__ u32 fmono(float f) {
    u32 u = __float_as_uint(f);
    return (u & 0x80000000u) ? ~u : (u | 0x80000000u);  // order-preserving bits
}

// ---- Kernel A (fused): per-image LDS histogram -> threshold -> compact ----
// One 1024-thread block per image. Replaces memset+hist+thresh+compact
// (4 graph nodes -> 1). No global atomics, no zeroed workspace.
__global__ __launch_bounds__(1024) void prep_kernel(const float* __restrict__ logits,
                                                    u32* __restrict__ cnt,
                                                    u64* __restrict__ cand) {
    __shared__ u32 lh[2][HREP];     // dual sub-histograms (lane-parity split)
    __shared__ u32 parts[1024];
    __shared__ u32 s_B;
    __shared__ u32 s_cnt;
    const int b = blockIdx.x;
    const int tid = threadIdx.x;
    u32* h0 = lh[0];
    u32* h1 = lh[1];

    // zero LDS hist + candidate counter
    for (int i = tid; i < 2 * HREP; i += 1024) ((u32*)lh)[i] = 0;
    if (tid == 0) s_cnt = 0;
    __syncthreads();

    const float4* src4 = (const float4*)(logits + (size_t)b * NANCH);
    u32* myh = lh[tid & 1];   // halve same-address atomic serialization

#define H1_(f) do { u32 m_ = fmono(f); atomicAdd(&myh[m_ >> 20], 1u); } while (0)
#define HIST4_(v) do { H1_((v).x); H1_((v).y); H1_((v).z); H1_((v).w); } while (0)

    // phase 1: 22500 float4 per image, 4 loads in flight per thread
    for (int j = 0; j < 20; j += 4) {
        float4 va = src4[tid + (j + 0) * 1024];
        float4 vb = src4[tid + (j + 1) * 1024];
        float4 vc = src4[tid + (j + 2) * 1024];
        float4 vd = src4[tid + (j + 3) * 1024];
        HIST4_(va); HIST4_(vb); HIST4_(vc); HIST4_(vd);
    }
    {
        float4 ve = src4[tid + 20 * 1024];          // max idx 21503 < 22500
        HIST4_(ve);
        if (tid < NF4 - 21 * 1024) {                // 996 tail float4s
            float4 vf = src4[tid + 21 * 1024];
            HIST4_(vf);
        }
    }
    __syncthreads();

    // phase 2: threshold bin B s.t. count(bin >= B) >= KEEP_PRE (maximal B)
    {
        int g = tid * 4;
        parts[tid] = h0[g] + h1[g] + h0[g + 1] + h1[g + 1]
                   + h0[g + 2] + h1[g + 2] + h0[g + 3] + h1[g + 3];
    }
    __syncthreads();
    if (tid < 64) {
        u32 g64 = 0;
#pragma unroll
        for (int k = 0; k < 16; k++) g64 += parts[tid * 16 + k];  // bins [64t,64t+64)
        // inclusive suffix-sum across the wave
        u32 s = g64;
#pragma unroll
        for (int off = 1; off < 64; off <<= 1) {
            u32 x = __shfl_down(s, off);
            if (tid + off < 64) s += x;
        }
        // unique crossing lane: count(>=group) >= K, count(>=next group) < K
        if (s >= KEEP_PRE && (s - g64) < KEEP_PRE) {
            u32 cum = s - g64;          // count strictly above this group
            int stop = tid * 64;
            int bin = stop + 63;
            u32 B = (u32)stop;
            for (; bin >= stop; bin--) {
                u32 hb = h0[bin] + h1[bin];
                if (cum + hb >= KEEP_PRE) { B = (u32)bin; break; }
                cum += hb;
            }
            s_B = B;
        }
    }
    __syncthreads();
    const u32 B = s_B;

    // phase 3: compact candidates (key = monotone<<32 | ~idx); logits L2-hot
    const u32 lane = tid & 63;
    u64* dst = cand + (size_t)b * CAND_MAX;
    for (int j = 0; j < 22; ++j) {
        int idx4 = tid + (j << 10);
        bool inb = idx4 < NF4;
        float4 v = make_float4(0.f, 0.f, 0.f, 0.f);
        if (inb) v = src4[idx4];
        u32 mm[4];
        mm[0] = fmono(v.x); mm[1] = fmono(v.y); mm[2] = fmono(v.z); mm[3] = fmono(v.w);
#pragma unroll
        for (int k = 0; k < 4; k++) {
            bool is = inb && ((mm[k] >> 20) >= B);
            u64 bal = __ballot(is);
            if (bal) {
                u32 old = 0;
                if (lane == 0) old = atomicAdd(&s_cnt, (u32)__popcll(bal));
                u32 wbase = __shfl(old, 0);
                if (is) {
                    u32 prefix = (u32)__popcll(bal & ((1ull << lane) - 1ull));
                    u32 pos = wbase + prefix;
                    u32 i = (u32)(idx4 * 4 + k);
                    if (pos < CAND_MAX)
                        dst[pos] = ((u64)mm[k] << 32) | (u32)(~i);
                }
            }
        }
    }
    __syncthreads();
    if (tid == 0) cnt[b * CNT_STRIDE] = s_cnt;
#undef H1_
#undef HIST4_
}

// ---- Kernel D: rank-select top 1000, sliced across NSLICE CUs per image ----
// rank(key) = #(strictly greater keys); keys unique -> permutation. keys[j]
// reads are wave-uniform -> LDS broadcast (cheap); cost is the compare chain.
__global__ __launch_bounds__(256) void select_kernel(const float* __restrict__ deltas,
                                                     const float* __restrict__ anchors,
                                                     const u32* __restrict__ cnt,
                                                     const u64* __restrict__ cand,
                                                     float4* __restrict__ selbox,
                                                     float* __restrict__ selscore,
                                                     const int* __restrict__ p_img_h,
                                                     const int* __restrict__ p_img_w) {
    __shared__ u64 keys[CAND_MAX];
    const int b = blockIdx.y;
    const int slice = blockIdx.x;                    // 0..NSLICE-1
    const int n = (int)min(cnt[b * CNT_STRIDE], (u32)CAND_MAX);
    const u64* src = cand + (size_t)b * CAND_MAX;
    for (int i = threadIdx.x; i < n; i += 256)
        keys[i] = src[i];
    __syncthreads();
    const int per = (n + NSLICE - 1) / NSLICE;
    const int i0 = slice * per;
    const int i1 = min(i0 + per, n);
    const float W = (float)(*p_img_w);
    const float H = (float)(*p_img_h);
    const float4* d4 = (const float4*)deltas;
    const float4* a4 = (const float4*)anchors;
    for (int i = i0 + threadIdx.x; i < i1; i += 256) {
        const u64 me = keys[i];
        int rank = 0;
        int j = 0;
        for (; j + 16 <= n; j += 16) {
            int r0 = 0;
#pragma unroll
            for (int k = 0; k < 16; k++) r0 += (keys[j + k] > me);
            rank += r0;
        }
        for (; j < n; j++) rank += (keys[j] > me);
        if (rank < KEEP_PRE) {
            u32 idx = ~(u32)me;
            u32 m = (u32)(me >> 32);
            u32 ub = (m & 0x80000000u) ? (m ^ 0x80000000u) : ~m;
            float logit = __uint_as_float(ub);
            float score = 1.0f / (1.0f + expf(-logit));
            float4 d = d4[(size_t)b * NANCH + idx];
            float4 a = a4[idx];
            float aw = a.z - a.x, ah = a.w - a.y;
            float acx = a.x + 0.5f * aw, acy = a.y + 0.5f * ah;
            float cx = d.x * aw + acx, cy = d.y * ah + acy;
            float w = expf(d.z) * aw, h = expf(d.w) * ah;
            float x1 = cx - 0.5f * w, y1 = cy - 0.5f * h;
            float x2 = cx + 0.5f * w, y2 = cy + 0.5f * h;
            x1 = fminf(fmaxf(x1, 0.0f), W); y1 = fminf(fmaxf(y1, 0.0f), H);
            x2 = fminf(fmaxf(x2, 0.0f), W); y2 = fminf(fmaxf(y2, 0.0f), H);
            selbox[(size_t)b * KEEP_PRE + rank] = make_float4(x1, y1, x2, y2);
            selscore[(size_t)b * KEEP_PRE + rank] = score;
        }
    }
}

// ---- Kernel E: IoU>thr suppression bitmask, mask[b][i][w] covers cols 64w..64w+63
// Only the 40 useful (i-chunk c, word w) pairs per image are launched: words
// w < 4c are entirely j < i (all-zero) and are skipped -> nms masks them out.
__global__ __launch_bounds__(256) void iou_kernel(const float4* __restrict__ selbox,
                                                  u64* __restrict__ mask) {
    const int b = blockIdx.y;
    const int bx = blockIdx.x;                       // 0..39 -> (c, w), w >= 4c
    int c, w;
    if (bx < 16)      { c = 0; w = bx; }
    else if (bx < 28) { c = 1; w = bx - 12; }        // w = 4 + (bx-16)
    else if (bx < 36) { c = 2; w = bx - 20; }        // w = 8 + (bx-28)
    else              { c = 3; w = bx - 24; }        // w = 12 + (bx-36)
    const int i = c * 256 + threadIdx.x;
    __shared__ float4 cb[64];
    __shared__ float ca[64];
    if (threadIdx.x < 64) {
        int j = w * 64 + threadIdx.x;
        float4 bx4 = (j < KEEP_PRE) ? selbox[(size_t)b * KEEP_PRE + j]
                                    : make_float4(0, 0, 0, 0);
        cb[threadIdx.x] = bx4;
        ca[threadIdx.x] = (bx4.z - bx4.x) * (bx4.w - bx4.y);
    }
    __syncthreads();
    if (i >= KEEP_PRE) return;
    float4 bi = selbox[(size_t)b * KEEP_PRE + i];
    float ai = (bi.z - bi.x) * (bi.w - bi.y);
    const int jbase = w * 64;
    u64 bits = 0;
#pragma unroll 8
    for (int jj = 0; jj < 64; jj++) {
        float4 bj = cb[jj];
        float ltx = fmaxf(bi.x, bj.x), lty = fmaxf(bi.y, bj.y);
        float rbx = fminf(bi.z, bj.z), rby = fminf(bi.w, bj.w);
        float wx = fmaxf(rbx - ltx, 0.0f), wy = fmaxf(rby - lty, 0.0f);
        float inter = wx * wy;
        float denom = ai + ca[jj] - inter + 1e-12f;
        // exact same rounding as reference: true division, compare to 0.7
        if (inter / denom > NMS_THR) bits |= (1ull << jj);
    }
    // mask to the valid window (i, KEEP_PRE)
    int lo = i + 1 - jbase;
    u64 mlo = (lo <= 0) ? ~0ull : ((lo >= 64) ? 0ull : (~0ull << lo));
    int hi = KEEP_PRE - jbase;                       // >= 40 always
    u64 mhi = (hi >= 64) ? ~0ull : ((1ull << hi) - 1ull);
    mask[((size_t)b * KEEP_PRE + i) * MW + w] = bits & mlo & mhi;
}

// ---- Kernel F: sequential greedy NMS, word-aligned branchless scan ----
#define CH_ROWS 64
#define CH_WORDS (CH_ROWS * MW)          // 1024 u64 = 8 KB
#define NCHUNK ((KEEP_PRE + CH_ROWS - 1) / CH_ROWS)   // 16 (last chunk 40 rows)

__global__ __launch_bounds__(256) void nms_out_kernel(const u64* __restrict__ mask,
                                                      const float4* __restrict__ selbox,
                                                      const float* __restrict__ selscore,
                                                      float* __restrict__ out) {
    const int b = blockIdx.x;
    __shared__ u64 lbuf[2][CH_WORDS];
    __shared__ u64 keepw[MW];
    __shared__ u32 wpre[MW + 1];
    __shared__ int ls_stop;
    const int tid = threadIdx.x;
    const u64* mrow = mask + (size_t)b * KEEP_PRE * MW;

    auto load_chunk = [&](int c) {
        int idx = tid - 128;
        if (idx < 0) return;
        const int words = (c == NCHUNK - 1)
                            ? (KEEP_PRE - (NCHUNK - 1) * CH_ROWS) * MW   // 640
                            : CH_WORDS;                                  // 1024
        const u64* gsrc = mrow + (size_t)c * CH_WORDS;
        u64* dst = lbuf[c & 1];
#pragma unroll
        for (int k = 0; k < 4; k++) {
            int off = k * 256 + idx * 2;
            ulonglong2 v;
            if (off < words) v = *(const ulonglong2*)(gsrc + off);
            else { v.x = 0ull; v.y = 0ull; }
            *(ulonglong2*)(dst + off) = v;
        }
    };

    if (tid == 0) ls_stop = 0;
    load_chunk(0);
    __syncthreads();

    u64 remv = 0;
    int kept_total = 0;
    const int lw = tid & 15;
    for (int c = 0; c < NCHUNK; c++) {
        if (c + 1 < NCHUNK) load_chunk(c + 1);
        if (tid < 64) {
            const u64* lb = lbuf[c & 1];
            // iou_kernel only writes words w >= 4*(c>>2) for rows of this
            // chunk; everything below is workspace garbage -> mask it off.
            const int wmin = (c >> 2) << 2;
            const u64 vmask = (lw >= wmin) ? ~0ull : 0ull;
            u64 cur = __shfl(remv, c);   // word c of accumulated suppression
#pragma unroll
            for (int blk = 0; blk < 8; blk++) {
                u64 R[8], rwv[8];
#pragma unroll
                for (int k = 0; k < 8; k++)
                    R[k] = lb[(size_t)(blk * 8 + k) * MW + lw] & vmask;   // lane word
#pragma unroll
                for (int k = 0; k < 8; k++)
                    rwv[k] = lb[(size_t)(blk * 8 + k) * MW + c];      // broadcast word c
#pragma unroll
                for (int k = 0; k < 8; k++) {
                    const int p = blk * 8 + k;                        // compile-time
                    u64 msk = ((cur >> p) & 1ull) ? 0ull : ~0ull;
                    remv |= R[k] & msk;
                    cur  |= rwv[k] & msk;
                }
            }
            kept_total += 64 - (int)__popcll(cur);
            if (c + 1 < NCHUNK && kept_total >= KEEP_POST) {
                if (lw > c) remv = ~0ull;     // force-suppress unprocessed rows
                if (tid == 0) ls_stop = 1;
            }
        }
        __syncthreads();
        if (ls_stop) break;
    }

    if (tid < MW) {
        u64 kw = ~remv;
        if (tid == MW - 1) kw &= (1ull << (KEEP_PRE - 64 * (MW - 1))) - 1ull;
        keepw[tid] = kw;
    }
    __syncthreads();
    if (tid == 0) {
        u32 cnt = 0;
        for (int w = 0; w < MW; w++) { wpre[w] = cnt; cnt += (u32)__popcll(keepw[w]); }
        wpre[MW] = cnt;
    }
    __syncthreads();
    const int total = (int)wpre[MW];
    float* outb = out + (size_t)b * KEEP_POST * 5;
    for (int i = tid; i < KEEP_PRE; i += 256) {
        int w = i >> 6;
        u64 kw = keepw[w];
        if ((kw >> (i & 63)) & 1ull) {
            int rank = (int)wpre[w] + __popcll(kw & ((1ull << (i & 63)) - 1ull));
            if (rank < KEEP_POST) {
                float4 bx = selbox[(size_t)b * KEEP_PRE + i];
                float sc = selscore[(size_t)b * KEEP_PRE + i];
                outb[rank * 5 + 0] = bx.x;
                outb[rank * 5 + 1] = bx.y;
                outb[rank * 5 + 2] = bx.z;
                outb[rank * 5 + 3] = bx.w;
                outb[rank * 5 + 4] = sc;
            }
        }
    }
    for (int r = tid; r < KEEP_POST; r += 256) {
        if (r >= total) {
            outb[r * 5 + 0] = 0.0f;
            outb[r * 5 + 1] = 0.0f;
            outb[r * 5 + 2] = 0.0f;
            outb[r * 5 + 3] = 0.0f;
            outb[r * 5 + 4] = 0.0f;
        }
    }
}

extern "C" void kernel_launch(void* const* d_in, const int* in_sizes, int n_in,
                              void* d_out, int out_size, void* d_ws, size_t ws_size,
                              hipStream_t stream) {
    const float* logits  = (const float*)d_in[0];   // [32,90000,1]
    const float* deltas  = (const float*)d_in[1];   // [32,90000,4]
    const float* anchors = (const float*)d_in[2];   // [90000,4]
    const int* p_img_h   = (const int*)d_in[3];
    const int* p_img_w   = (const int*)d_in[4];

    char* ws = (char*)d_ws;
    u32* cnt       = (u32*)(ws + CNT_OFF);
    u64* cand      = (u64*)(ws + CAND_OFF);
    float4* selbox = (float4*)(ws + BOX_OFF);
    float* selscore = (float*)(ws + SCORE_OFF);
    u64* mask      = (u64*)(ws + MASK_OFF);

    // 4 graph nodes, no memset: nothing in the workspace needs pre-zeroing.
    prep_kernel<<<dim3(BS), 1024, 0, stream>>>(logits, cnt, cand);
    select_kernel<<<dim3(NSLICE, BS), 256, 0, stream>>>(deltas, anchors, cnt, cand,
                                                        selbox, selscore, p_img_h, p_img_w);
    iou_kernel<<<dim3(40, BS), 256, 0, stream>>>(selbox, mask);
    nms_out_kernel<<<BS, 256, 0, stream>>>(mask, selbox, selscore, (float*)d_out);
}

// Round 2
// 170.281 us; speedup vs baseline: 1.0998x; 1.0454x over previous
//
#include <hip/hip_runtime.h>
#include <stdint.h>

// Mimic numpy (no FMA contraction) for all math feeding discrete decisions.
#pragma clang fp contract(off)

#define BS 32
#define NANCH 90000
#define KEEP_PRE 1000
#define KEEP_POST 300
#define NMS_THR 0.7f
#define NBINS 4096      // top-12-bit histogram of monotone float bits
#define HREP 4129       // NBINS + 33 pad: copy1 lands on shifted banks
#define CAND_MAX 4096
#define MW 16           // u64 mask words per NMS row (16*64 = 1024 >= 1000)
#define NF4 22500       // NANCH / 4 float4s per image

typedef unsigned long long u64;
typedef unsigned int u32;

// ---- workspace layout (bytes); nothing needs pre-zeroing ----
#define BOX_OFF    0                                        // float4[BS][KEEP_PRE]
#define SCORE_OFF  (BOX_OFF + (size_t)BS * KEEP_PRE * 16)   // float[BS][KEEP_PRE]
#define MASK_OFF   (SCORE_OFF + (size_t)BS * KEEP_PRE * 4)  // u64[BS][KEEP_PRE][MW]
// total ~4.7 MB

__device__ __forceinline__ u32 fmono(float f) {
    u32 u = __float_as_uint(f);
    return (u & 0x80000000u) ? ~u : (u | 0x80000000u);  // order-preserving bits
}

// ---- Kernel A (fused): hist -> suffix-scan -> threshold -> grouped compact
//      -> histogram-rank -> decode/clip -> selbox/selscore.
// One 1024-thread block per image; everything stays in LDS (~82 KB).
// rank(key) = #(strictly greater keys) = S[bin+1] + #(greater in own bin).
__global__ __launch_bounds__(1024) void prep_kernel(const float* __restrict__ logits,
                                                    const float* __restrict__ deltas,
                                                    const float* __restrict__ anchors,
                                                    float4* __restrict__ selbox,
                                                    float* __restrict__ selscore,
                                                    const int* __restrict__ p_img_h,
                                                    const int* __restrict__ p_img_w) {
    __shared__ u32 lh[2][HREP];     // dual sub-histograms (lane-parity split)
    __shared__ u32 S[NBINS + 1];    // suffix counts: S[b] = #keys with bin >= b
    __shared__ u64 grp[CAND_MAX];   // candidates grouped by bin at rank-base
    __shared__ u32 wtot[16], wexc[16];
    __shared__ u32 s_B;
    const int b = blockIdx.x;
    const int tid = threadIdx.x;
    const u32 lane = tid & 63;
    const int wv = tid >> 6;
    u32* h0 = lh[0];
    u32* h1 = lh[1];

    for (int i = tid; i < 2 * HREP; i += 1024) ((u32*)lh)[i] = 0;
    __syncthreads();

    const float4* src4 = (const float4*)(logits + (size_t)b * NANCH);
    u32* myh = lh[tid & 1];   // halve same-address atomic serialization

#define H1_(f) do { u32 m_ = fmono(f); atomicAdd(&myh[m_ >> 20], 1u); } while (0)
#define HIST4_(v) do { H1_((v).x); H1_((v).y); H1_((v).z); H1_((v).w); } while (0)

    // phase 1: histogram 22500 float4 per image, 4 loads in flight
    for (int j = 0; j < 20; j += 4) {
        float4 va = src4[tid + (j + 0) * 1024];
        float4 vb = src4[tid + (j + 1) * 1024];
        float4 vc = src4[tid + (j + 2) * 1024];
        float4 vd = src4[tid + (j + 3) * 1024];
        HIST4_(va); HIST4_(vb); HIST4_(vc); HIST4_(vd);
    }
    {
        float4 ve = src4[tid + 20 * 1024];          // max idx 21503 < 22500
        HIST4_(ve);
        if (tid < NF4 - 21 * 1024) {                // 996 tail float4s
            float4 vf = src4[tid + 21 * 1024];
            HIST4_(vf);
        }
    }
    __syncthreads();

    // phase 2a: block-wide suffix sum over 4096 bins (4 bins/thread)
    const int g = tid * 4;
    const u32 c0 = h0[g] + h1[g];
    const u32 c1 = h0[g + 1] + h1[g + 1];
    const u32 c2 = h0[g + 2] + h1[g + 2];
    const u32 c3 = h0[g + 3] + h1[g + 3];
    {
        u32 s = c0 + c1 + c2 + c3;
#pragma unroll
        for (int off = 1; off < 64; off <<= 1) {    // wave inclusive suffix scan
            u32 x = __shfl_down(s, off);
            if (lane + off < 64) s += x;
        }
        if (lane == 0) wtot[wv] = s;                // wave total
        __syncthreads();
        if (tid < 16) {                             // exclusive suffix of wave totals
            u32 v = wtot[tid];
            u32 t = v;
#pragma unroll
            for (int off = 1; off < 16; off <<= 1) {
                u32 x = __shfl_down(t, off);
                if (tid + off < 16) t += x;
            }
            wexc[tid] = t - v;
        }
        __syncthreads();
        const u32 base = wexc[wv] + s;              // #keys with bin >= 4*tid
        S[g]     = base;
        S[g + 1] = base - c0;
        S[g + 2] = base - c0 - c1;
        S[g + 3] = base - c0 - c1 - c2;
        if (tid == 1023) S[NBINS] = 0;
    }
    __syncthreads();

    // phase 2b: threshold B = max bin with S[B] >= KEEP_PRE; zero fill counters
    {
#pragma unroll
        for (int k = 0; k < 4; k++) {
            int bin = g + k;
            if (S[bin] >= KEEP_PRE && S[bin + 1] < KEEP_PRE) s_B = (u32)bin;
        }
        // h0/h1 no longer needed -> reuse lh[0] as per-bin fill counters
        h0[g] = 0; h0[g + 1] = 0; h0[g + 2] = 0; h0[g + 3] = 0;
    }
    __syncthreads();
    const u32 B = s_B;
    const int n_cap = (int)min(S[B], (u32)CAND_MAX);
    u32* fill = h0;

    // phase 3: grouped compaction (logits L2-hot). slot = S[bin+1] + fill[bin]++
    for (int j = 0; j < 22; ++j) {
        int idx4 = tid + (j << 10);
        if (idx4 >= NF4) break;
        float4 v = src4[idx4];
        u32 mm[4];
        mm[0] = fmono(v.x); mm[1] = fmono(v.y); mm[2] = fmono(v.z); mm[3] = fmono(v.w);
#pragma unroll
        for (int k = 0; k < 4; k++) {
            u32 bin = mm[k] >> 20;
            if (bin >= B) {
                u32 pos = S[bin + 1] + atomicAdd(&fill[bin], 1u);
                u32 i = (u32)(idx4 * 4 + k);
                if (pos < (u32)CAND_MAX)
                    grp[pos] = ((u64)mm[k] << 32) | (u32)(~i);
            }
        }
    }
    __syncthreads();

    // phase 4: exact rank within own bin-group, then decode + clip + write
    const float W = (float)(*p_img_w);
    const float H = (float)(*p_img_h);
    const float4* d4 = (const float4*)deltas;
    const float4* a4 = (const float4*)anchors;
    for (int p = tid; p < n_cap; p += 1024) {
        const u64 me = grp[p];
        const int bin = (int)(me >> 52);
        const int gb = (int)S[bin + 1];
        const int ge = min((int)S[bin], n_cap);
        int rank = gb;
        int q = gb;
        for (; q + 4 <= ge; q += 4) {
            rank += (grp[q] > me) + (grp[q + 1] > me)
                  + (grp[q + 2] > me) + (grp[q + 3] > me);
        }
        for (; q < ge; q++) rank += (grp[q] > me);
        if (rank < KEEP_PRE) {
            u32 idx = ~(u32)me;
            u32 m = (u32)(me >> 32);
            u32 ub = (m & 0x80000000u) ? (m ^ 0x80000000u) : ~m;
            float logit = __uint_as_float(ub);
            float score = 1.0f / (1.0f + expf(-logit));
            float4 d = d4[(size_t)b * NANCH + idx];
            float4 a = a4[idx];
            float aw = a.z - a.x, ah = a.w - a.y;
            float acx = a.x + 0.5f * aw, acy = a.y + 0.5f * ah;
            float cx = d.x * aw + acx, cy = d.y * ah + acy;
            float w = expf(d.z) * aw, h = expf(d.w) * ah;
            float x1 = cx - 0.5f * w, y1 = cy - 0.5f * h;
            float x2 = cx + 0.5f * w, y2 = cy + 0.5f * h;
            x1 = fminf(fmaxf(x1, 0.0f), W); y1 = fminf(fmaxf(y1, 0.0f), H);
            x2 = fminf(fmaxf(x2, 0.0f), W); y2 = fminf(fmaxf(y2, 0.0f), H);
            selbox[(size_t)b * KEEP_PRE + rank] = make_float4(x1, y1, x2, y2);
            selscore[(size_t)b * KEEP_PRE + rank] = score;
        }
    }
#undef H1_
#undef HIST4_
}

// ---- Kernel E: IoU>thr suppression bitmask, mask[b][i][w] covers cols 64w..64w+63
// Only the 40 useful (i-chunk c, word w) pairs per image are launched: words
// w < 4c are entirely j < i (all-zero) and are skipped -> nms masks them out.
__global__ __launch_bounds__(256) void iou_kernel(const float4* __restrict__ selbox,
                                                  u64* __restrict__ mask) {
    const int b = blockIdx.y;
    const int bx = blockIdx.x;                       // 0..39 -> (c, w), w >= 4c
    int c, w;
    if (bx < 16)      { c = 0; w = bx; }
    else if (bx < 28) { c = 1; w = bx - 12; }        // w = 4 + (bx-16)
    else if (bx < 36) { c = 2; w = bx - 20; }        // w = 8 + (bx-28)
    else              { c = 3; w = bx - 24; }        // w = 12 + (bx-36)
    const int i = c * 256 + threadIdx.x;
    __shared__ float4 cb[64];
    __shared__ float ca[64];
    if (threadIdx.x < 64) {
        int j = w * 64 + threadIdx.x;
        float4 bx4 = (j < KEEP_PRE) ? selbox[(size_t)b * KEEP_PRE + j]
                                    : make_float4(0, 0, 0, 0);
        cb[threadIdx.x] = bx4;
        ca[threadIdx.x] = (bx4.z - bx4.x) * (bx4.w - bx4.y);
    }
    __syncthreads();
    if (i >= KEEP_PRE) return;
    float4 bi = selbox[(size_t)b * KEEP_PRE + i];
    float ai = (bi.z - bi.x) * (bi.w - bi.y);
    const int jbase = w * 64;
    u64 bits = 0;
#pragma unroll 8
    for (int jj = 0; jj < 64; jj++) {
        float4 bj = cb[jj];
        float ltx = fmaxf(bi.x, bj.x), lty = fmaxf(bi.y, bj.y);
        float rbx = fminf(bi.z, bj.z), rby = fminf(bi.w, bj.w);
        float wx = fmaxf(rbx - ltx, 0.0f), wy = fmaxf(rby - lty, 0.0f);
        float inter = wx * wy;
        float denom = ai + ca[jj] - inter + 1e-12f;
        // exact same rounding as reference: true division, compare to 0.7
        if (inter / denom > NMS_THR) bits |= (1ull << jj);
    }
    // mask to the valid window (i, KEEP_PRE)
    int lo = i + 1 - jbase;
    u64 mlo = (lo <= 0) ? ~0ull : ((lo >= 64) ? 0ull : (~0ull << lo));
    int hi = KEEP_PRE - jbase;                       // >= 40 always
    u64 mhi = (hi >= 64) ? ~0ull : ((1ull << hi) - 1ull);
    mask[((size_t)b * KEEP_PRE + i) * MW + w] = bits & mlo & mhi;
}

// ---- Kernel F: sequential greedy NMS, word-aligned branchless scan ----
#define CH_ROWS 64
#define CH_WORDS (CH_ROWS * MW)          // 1024 u64 = 8 KB
#define NCHUNK ((KEEP_PRE + CH_ROWS - 1) / CH_ROWS)   // 16 (last chunk 40 rows)

__global__ __launch_bounds__(256) void nms_out_kernel(const u64* __restrict__ mask,
                                                      const float4* __restrict__ selbox,
                                                      const float* __restrict__ selscore,
                                                      float* __restrict__ out) {
    const int b = blockIdx.x;
    __shared__ u64 lbuf[2][CH_WORDS];
    __shared__ u64 keepw[MW];
    __shared__ u32 wpre[MW + 1];
    __shared__ int ls_stop;
    const int tid = threadIdx.x;
    const u64* mrow = mask + (size_t)b * KEEP_PRE * MW;

    auto load_chunk = [&](int c) {
        int idx = tid - 128;
        if (idx < 0) return;
        const int words = (c == NCHUNK - 1)
                            ? (KEEP_PRE - (NCHUNK - 1) * CH_ROWS) * MW   // 640
                            : CH_WORDS;                                  // 1024
        const u64* gsrc = mrow + (size_t)c * CH_WORDS;
        u64* dst = lbuf[c & 1];
#pragma unroll
        for (int k = 0; k < 4; k++) {
            int off = k * 256 + idx * 2;
            ulonglong2 v;
            if (off < words) v = *(const ulonglong2*)(gsrc + off);
            else { v.x = 0ull; v.y = 0ull; }
            *(ulonglong2*)(dst + off) = v;
        }
    };

    if (tid == 0) ls_stop = 0;
    load_chunk(0);
    __syncthreads();

    u64 remv = 0;
    int kept_total = 0;
    const int lw = tid & 15;
    for (int c = 0; c < NCHUNK; c++) {
        if (c + 1 < NCHUNK) load_chunk(c + 1);
        if (tid < 64) {
            const u64* lb = lbuf[c & 1];
            // iou_kernel only writes words w >= 4*(c>>2) for rows of this
            // chunk; everything below is workspace garbage -> mask it off.
            const int wmin = (c >> 2) << 2;
            const u64 vmask = (lw >= wmin) ? ~0ull : 0ull;
            u64 cur = __shfl(remv, c);   // word c of accumulated suppression
#pragma unroll
            for (int blk = 0; blk < 8; blk++) {
                u64 R[8], rwv[8];
#pragma unroll
                for (int k = 0; k < 8; k++)
                    R[k] = lb[(size_t)(blk * 8 + k) * MW + lw] & vmask;   // lane word
#pragma unroll
                for (int k = 0; k < 8; k++)
                    rwv[k] = lb[(size_t)(blk * 8 + k) * MW + c];      // broadcast word c
#pragma unroll
                for (int k = 0; k < 8; k++) {
                    const int p = blk * 8 + k;                        // compile-time
                    u64 msk = ((cur >> p) & 1ull) ? 0ull : ~0ull;
                    remv |= R[k] & msk;
                    cur  |= rwv[k] & msk;
                }
            }
            kept_total += 64 - (int)__popcll(cur);
            if (c + 1 < NCHUNK && kept_total >= KEEP_POST) {
                if (lw > c) remv = ~0ull;     // force-suppress unprocessed rows
                if (tid == 0) ls_stop = 1;
            }
        }
        __syncthreads();
        if (ls_stop) break;
    }

    if (tid < MW) {
        u64 kw = ~remv;
        if (tid == MW - 1) kw &= (1ull << (KEEP_PRE - 64 * (MW - 1))) - 1ull;
        keepw[tid] = kw;
    }
    __syncthreads();
    if (tid == 0) {
        u32 cnt = 0;
        for (int w = 0; w < MW; w++) { wpre[w] = cnt; cnt += (u32)__popcll(keepw[w]); }
        wpre[MW] = cnt;
    }
    __syncthreads();
    const int total = (int)wpre[MW];
    float* outb = out + (size_t)b * KEEP_POST * 5;
    for (int i = tid; i < KEEP_PRE; i += 256) {
        int w = i >> 6;
        u64 kw = keepw[w];
        if ((kw >> (i & 63)) & 1ull) {
            int rank = (int)wpre[w] + __popcll(kw & ((1ull << (i & 63)) - 1ull));
            if (rank < KEEP_POST) {
                float4 bx = selbox[(size_t)b * KEEP_PRE + i];
                float sc = selscore[(size_t)b * KEEP_PRE + i];
                outb[rank * 5 + 0] = bx.x;
                outb[rank * 5 + 1] = bx.y;
                outb[rank * 5 + 2] = bx.z;
                outb[rank * 5 + 3] = bx.w;
                outb[rank * 5 + 4] = sc;
            }
        }
    }
    for (int r = tid; r < KEEP_POST; r += 256) {
        if (r >= total) {
            outb[r * 5 + 0] = 0.0f;
            outb[r * 5 + 1] = 0.0f;
            outb[r * 5 + 2] = 0.0f;
            outb[r * 5 + 3] = 0.0f;
            outb[r * 5 + 4] = 0.0f;
        }
    }
}

extern "C" void kernel_launch(void* const* d_in, const int* in_sizes, int n_in,
                              void* d_out, int out_size, void* d_ws, size_t ws_size,
                              hipStream_t stream) {
    const float* logits  = (const float*)d_in[0];   // [32,90000,1]
    const float* deltas  = (const float*)d_in[1];   // [32,90000,4]
    const float* anchors = (const float*)d_in[2];   // [90000,4]
    const int* p_img_h   = (const int*)d_in[3];
    const int* p_img_w   = (const int*)d_in[4];

    char* ws = (char*)d_ws;
    float4* selbox  = (float4*)(ws + BOX_OFF);
    float* selscore = (float*)(ws + SCORE_OFF);
    u64* mask       = (u64*)(ws + MASK_OFF);

    // 3 graph nodes; select is fused into prep via histogram ranking.
    prep_kernel<<<dim3(BS), 1024, 0, stream>>>(logits, deltas, anchors,
                                               selbox, selscore, p_img_h, p_img_w);
    iou_kernel<<<dim3(40, BS), 256, 0, stream>>>(selbox, mask);
    nms_out_kernel<<<BS, 256, 0, stream>>>(mask, selbox, selscore, (float*)d_out);
}

// Round 3
// 159.083 us; speedup vs baseline: 1.1772x; 1.0704x over previous
//
#include <hip/hip_runtime.h>
#include <stdint.h>

// Mimic numpy (no FMA contraction) for all math feeding discrete decisions.
#pragma clang fp contract(off)

#define BS 32
#define NANCH 90000
#define KEEP_PRE 1000
#define KEEP_POST 300
#define NMS_THR 0.7f
#define NBINS 4096      // top-12-bit histogram of monotone float bits
#define HREP 4129       // NBINS + 33 pad: copies land on shifted banks
#define NCOPY 4         // sub-histogram copies (lane-parity split)
#define CAND_MAX 4096
#define MW 16           // u64 mask words per NMS row (16*64 = 1024 >= 1000)
#define NF4 22500       // NANCH / 4 float4s per image
#define NSL 8           // hist/compact slices per image
#define F4_PER_BLK ((NF4 + NSL - 1) / NSL)   // 2813

typedef unsigned long long u64;
typedef unsigned int u32;

// ---- workspace layout (bytes); nothing needs pre-zeroing ----
#define HISTG_OFF 0                                           // u32[BS][NSL][NBINS] 4 MB
#define SG_OFF    (HISTG_OFF + (size_t)BS * NSL * NBINS * 4)  // u32[BS][NBINS] 512 KB
#define GRP_OFF   (SG_OFF + (size_t)BS * NBINS * 4)           // u64[BS][CAND_MAX] 1 MB
#define BOX_OFF   (GRP_OFF + (size_t)BS * CAND_MAX * 8)       // float4[BS][KEEP_PRE]
#define SCORE_OFF (BOX_OFF + (size_t)BS * KEEP_PRE * 16)      // float[BS][KEEP_PRE]
#define MASK_OFF  (SCORE_OFF + (size_t)BS * KEEP_PRE * 4)     // u64[BS][KEEP_PRE][MW]
// total ~10.3 MB

__device__ __forceinline__ u32 fmono(float f) {
    u32 u = __float_as_uint(f);
    return (u & 0x80000000u) ? ~u : (u | 0x80000000u);  // order-preserving bits
}

// ---- Kernel H: per-(image, slice) LDS histogram of top-12 monotone bits ----
// 8 slices/image -> 256 blocks (whole machine); 4 sub-copies cut same-bin
// atomic serialization to ~1/4 per wave.
__global__ __launch_bounds__(1024) void hist8_kernel(const float* __restrict__ logits,
                                                     u32* __restrict__ histg) {
    __shared__ u32 lh[NCOPY][HREP];
    const int b = blockIdx.y, slice = blockIdx.x, tid = threadIdx.x;
    for (int i = tid; i < NCOPY * HREP; i += 1024) ((u32*)lh)[i] = 0;
    __syncthreads();
    const float4* src4 = (const float4*)(logits + (size_t)b * NANCH);
    const int f0 = slice * F4_PER_BLK;
    const int f1 = min(f0 + F4_PER_BLK, NF4);
    u32* myh = lh[tid & (NCOPY - 1)];
    for (int j = f0 + tid; j < f1; j += 1024) {
        float4 v = src4[j];
        atomicAdd(&myh[fmono(v.x) >> 20], 1u);
        atomicAdd(&myh[fmono(v.y) >> 20], 1u);
        atomicAdd(&myh[fmono(v.z) >> 20], 1u);
        atomicAdd(&myh[fmono(v.w) >> 20], 1u);
    }
    __syncthreads();
    u32* dst = histg + ((size_t)b * NSL + slice) * NBINS;
    for (int i = tid; i < NBINS; i += 1024)
        dst[i] = lh[0][i] + lh[1][i] + lh[2][i] + lh[3][i];
}

// ---- Kernel C: per-slice grouped compaction with exact precomputed ranges ----
// Each block reduces the 8 slice-histograms (L2-hot), suffix-scans S, finds
// threshold B, and derives its OWN disjoint per-bin write range:
//   start[bin] = S[bin+1] + sum_{k<slice} hist_k[bin]
// -> no cross-block atomics, no zeroed fill array. Slice 0 persists S.
__global__ __launch_bounds__(1024) void compact8_kernel(const float* __restrict__ logits,
                                                        const u32* __restrict__ histg,
                                                        u32* __restrict__ Sg,
                                                        u64* __restrict__ grp) {
    __shared__ u32 S[NBINS + 1];
    __shared__ u32 start[NBINS];
    __shared__ u32 wtot[16], wexc[16];
    __shared__ u32 s_B;
    const int b = blockIdx.y, slice = blockIdx.x, tid = threadIdx.x;
    const u32 lane = tid & 63;
    const int wv = tid >> 6;
    const int g = tid * 4;

    u32 c0 = 0, c1 = 0, c2 = 0, c3 = 0;      // per-bin totals over slices
    u32 p0 = 0, p1 = 0, p2 = 0, p3 = 0;      // prefix over slices < mine
    const u32* hb = histg + (size_t)b * NSL * NBINS;
#pragma unroll
    for (int k = 0; k < NSL; k++) {
        const uint4 h4 = *(const uint4*)(hb + (size_t)k * NBINS + g);
        c0 += h4.x; c1 += h4.y; c2 += h4.z; c3 += h4.w;
        if (k < slice) { p0 += h4.x; p1 += h4.y; p2 += h4.z; p3 += h4.w; }
    }
    // block-wide suffix sum over 4096 bins (4 bins/thread)
    u32 s = c0 + c1 + c2 + c3;
#pragma unroll
    for (int off = 1; off < 64; off <<= 1) {    // wave inclusive suffix scan
        u32 x = __shfl_down(s, off);
        if (lane + off < 64) s += x;
    }
    if (lane == 0) wtot[wv] = s;
    __syncthreads();
    if (tid < 16) {                             // exclusive suffix of wave totals
        u32 v = wtot[tid];
        u32 t = v;
#pragma unroll
        for (int off = 1; off < 16; off <<= 1) {
            u32 x = __shfl_down(t, off);
            if (tid + off < 16) t += x;
        }
        wexc[tid] = t - v;
    }
    __syncthreads();
    const u32 base = wexc[wv] + s;              // #keys with bin >= 4*tid
    S[g]     = base;
    S[g + 1] = base - c0;
    S[g + 2] = base - c0 - c1;
    S[g + 3] = base - c0 - c1 - c2;
    if (tid == 1023) S[NBINS] = 0;
    __syncthreads();

    // threshold B = max bin with S[B] >= KEEP_PRE; per-slice write bases
#pragma unroll
    for (int k = 0; k < 4; k++) {
        int bin = g + k;
        if (S[bin] >= KEEP_PRE && S[bin + 1] < KEEP_PRE) s_B = (u32)bin;
    }
    start[g]     = S[g + 1] + p0;
    start[g + 1] = S[g + 2] + p1;
    start[g + 2] = S[g + 3] + p2;
    start[g + 3] = S[g + 4] + p3;
    __syncthreads();
    const u32 B = s_B;

    if (slice == 0)
        *(uint4*)(Sg + (size_t)b * NBINS + g) =
            make_uint4(S[g], S[g + 1], S[g + 2], S[g + 3]);

    // element pass over own chunk: grouped compaction (logits L2-hot)
    const float4* src4 = (const float4*)(logits + (size_t)b * NANCH);
    const int f0 = slice * F4_PER_BLK;
    const int f1 = min(f0 + F4_PER_BLK, NF4);
    u64* dst = grp + (size_t)b * CAND_MAX;
    for (int j = f0 + tid; j < f1; j += 1024) {
        float4 v = src4[j];
        u32 mm[4];
        mm[0] = fmono(v.x); mm[1] = fmono(v.y); mm[2] = fmono(v.z); mm[3] = fmono(v.w);
#pragma unroll
        for (int k = 0; k < 4; k++) {
            u32 bin = mm[k] >> 20;
            if (bin >= B) {
                u32 pos = atomicAdd(&start[bin], 1u);   // within this slice's range
                u32 i = (u32)(j * 4 + k);
                if (pos < (u32)CAND_MAX)
                    dst[pos] = ((u64)mm[k] << 32) | (u32)(~i);
            }
        }
    }
}

// ---- Kernel R: exact rank within own bin-group, decode + clip + write ----
// rank(key) = S[bin+1] + #(greater keys in own bin-group).
__global__ __launch_bounds__(1024) void rank_kernel(const float* __restrict__ deltas,
                                                    const float* __restrict__ anchors,
                                                    const u32* __restrict__ Sg,
                                                    const u64* __restrict__ grpg,
                                                    float4* __restrict__ selbox,
                                                    float* __restrict__ selscore,
                                                    const int* __restrict__ p_img_h,
                                                    const int* __restrict__ p_img_w) {
    __shared__ u32 S[NBINS + 1];
    __shared__ u64 grp[CAND_MAX];
    __shared__ u32 s_B;
    const int b = blockIdx.x, tid = threadIdx.x;
    const int g = tid * 4;
    {
        uint4 v = *(const uint4*)(Sg + (size_t)b * NBINS + g);
        S[g] = v.x; S[g + 1] = v.y; S[g + 2] = v.z; S[g + 3] = v.w;
    }
    if (tid == 1023) S[NBINS] = 0;
    __syncthreads();
#pragma unroll
    for (int k = 0; k < 4; k++) {
        int bin = g + k;
        if (S[bin] >= KEEP_PRE && S[bin + 1] < KEEP_PRE) s_B = (u32)bin;
    }
    __syncthreads();
    const u32 B = s_B;
    const int n_cap = (int)min(S[B], (u32)CAND_MAX);
    const u64* src = grpg + (size_t)b * CAND_MAX;
    for (int i = tid; i < n_cap; i += 1024)
        grp[i] = src[i];
    __syncthreads();

    const float W = (float)(*p_img_w);
    const float H = (float)(*p_img_h);
    const float4* d4 = (const float4*)deltas;
    const float4* a4 = (const float4*)anchors;
    for (int p = tid; p < n_cap; p += 1024) {
        const u64 me = grp[p];
        const int bin = (int)(me >> 52);
        const int gb = (int)S[bin + 1];
        const int ge = min((int)S[bin], n_cap);
        int rank = gb;
        int q = gb;
        for (; q + 4 <= ge; q += 4) {
            rank += (grp[q] > me) + (grp[q + 1] > me)
                  + (grp[q + 2] > me) + (grp[q + 3] > me);
        }
        for (; q < ge; q++) rank += (grp[q] > me);
        if (rank < KEEP_PRE) {
            u32 idx = ~(u32)me;
            u32 m = (u32)(me >> 32);
            u32 ub = (m & 0x80000000u) ? (m ^ 0x80000000u) : ~m;
            float logit = __uint_as_float(ub);
            float score = 1.0f / (1.0f + expf(-logit));
            float4 d = d4[(size_t)b * NANCH + idx];
            float4 a = a4[idx];
            float aw = a.z - a.x, ah = a.w - a.y;
            float acx = a.x + 0.5f * aw, acy = a.y + 0.5f * ah;
            float cx = d.x * aw + acx, cy = d.y * ah + acy;
            float w = expf(d.z) * aw, h = expf(d.w) * ah;
            float x1 = cx - 0.5f * w, y1 = cy - 0.5f * h;
            float x2 = cx + 0.5f * w, y2 = cy + 0.5f * h;
            x1 = fminf(fmaxf(x1, 0.0f), W); y1 = fminf(fmaxf(y1, 0.0f), H);
            x2 = fminf(fmaxf(x2, 0.0f), W); y2 = fminf(fmaxf(y2, 0.0f), H);
            selbox[(size_t)b * KEEP_PRE + rank] = make_float4(x1, y1, x2, y2);
            selscore[(size_t)b * KEEP_PRE + rank] = score;
        }
    }
}

// ---- Kernel E: IoU>thr suppression bitmask, mask[b][i][w] covers cols 64w..64w+63
// Only the 40 useful (i-chunk c, word w) pairs per image are launched: words
// w < 4c are entirely j < i (all-zero) and are skipped -> nms masks them out.
__global__ __launch_bounds__(256) void iou_kernel(const float4* __restrict__ selbox,
                                                  u64* __restrict__ mask) {
    const int b = blockIdx.y;
    const int bx = blockIdx.x;                       // 0..39 -> (c, w), w >= 4c
    int c, w;
    if (bx < 16)      { c = 0; w = bx; }
    else if (bx < 28) { c = 1; w = bx - 12; }        // w = 4 + (bx-16)
    else if (bx < 36) { c = 2; w = bx - 20; }        // w = 8 + (bx-28)
    else              { c = 3; w = bx - 24; }        // w = 12 + (bx-36)
    const int i = c * 256 + threadIdx.x;
    __shared__ float4 cb[64];
    __shared__ float ca[64];
    if (threadIdx.x < 64) {
        int j = w * 64 + threadIdx.x;
        float4 bx4 = (j < KEEP_PRE) ? selbox[(size_t)b * KEEP_PRE + j]
                                    : make_float4(0, 0, 0, 0);
        cb[threadIdx.x] = bx4;
        ca[threadIdx.x] = (bx4.z - bx4.x) * (bx4.w - bx4.y);
    }
    __syncthreads();
    if (i >= KEEP_PRE) return;
    float4 bi = selbox[(size_t)b * KEEP_PRE + i];
    float ai = (bi.z - bi.x) * (bi.w - bi.y);
    const int jbase = w * 64;
    u64 bits = 0;
#pragma unroll 8
    for (int jj = 0; jj < 64; jj++) {
        float4 bj = cb[jj];
        float ltx = fmaxf(bi.x, bj.x), lty = fmaxf(bi.y, bj.y);
        float rbx = fminf(bi.z, bj.z), rby = fminf(bi.w, bj.w);
        float wx = fmaxf(rbx - ltx, 0.0f), wy = fmaxf(rby - lty, 0.0f);
        float inter = wx * wy;
        float denom = ai + ca[jj] - inter + 1e-12f;
        // exact same rounding as reference: true division, compare to 0.7
        if (inter / denom > NMS_THR) bits |= (1ull << jj);
    }
    // mask to the valid window (i, KEEP_PRE)
    int lo = i + 1 - jbase;
    u64 mlo = (lo <= 0) ? ~0ull : ((lo >= 64) ? 0ull : (~0ull << lo));
    int hi = KEEP_PRE - jbase;                       // >= 40 always
    u64 mhi = (hi >= 64) ? ~0ull : ((1ull << hi) - 1ull);
    mask[((size_t)b * KEEP_PRE + i) * MW + w] = bits & mlo & mhi;
}

// ---- Kernel F: sequential greedy NMS, word-aligned branchless scan ----
#define CH_ROWS 64
#define CH_WORDS (CH_ROWS * MW)          // 1024 u64 = 8 KB
#define NCHUNK ((KEEP_PRE + CH_ROWS - 1) / CH_ROWS)   // 16 (last chunk 40 rows)

__global__ __launch_bounds__(256) void nms_out_kernel(const u64* __restrict__ mask,
                                                      const float4* __restrict__ selbox,
                                                      const float* __restrict__ selscore,
                                                      float* __restrict__ out) {
    const int b = blockIdx.x;
    __shared__ u64 lbuf[2][CH_WORDS];
    __shared__ u64 keepw[MW];
    __shared__ u32 wpre[MW + 1];
    __shared__ int ls_stop;
    const int tid = threadIdx.x;
    const u64* mrow = mask + (size_t)b * KEEP_PRE * MW;

    auto load_chunk = [&](int c) {
        int idx = tid - 128;
        if (idx < 0) return;
        const int words = (c == NCHUNK - 1)
                            ? (KEEP_PRE - (NCHUNK - 1) * CH_ROWS) * MW   // 640
                            : CH_WORDS;                                  // 1024
        const u64* gsrc = mrow + (size_t)c * CH_WORDS;
        u64* dst = lbuf[c & 1];
#pragma unroll
        for (int k = 0; k < 4; k++) {
            int off = k * 256 + idx * 2;
            ulonglong2 v;
            if (off < words) v = *(const ulonglong2*)(gsrc + off);
            else { v.x = 0ull; v.y = 0ull; }
            *(ulonglong2*)(dst + off) = v;
        }
    };

    if (tid == 0) ls_stop = 0;
    load_chunk(0);
    __syncthreads();

    u64 remv = 0;
    int kept_total = 0;
    const int lw = tid & 15;
    for (int c = 0; c < NCHUNK; c++) {
        if (c + 1 < NCHUNK) load_chunk(c + 1);
        if (tid < 64) {
            const u64* lb = lbuf[c & 1];
            // iou_kernel only writes words w >= 4*(c>>2) for rows of this
            // chunk; everything below is workspace garbage -> mask it off.
            const int wmin = (c >> 2) << 2;
            const u64 vmask = (lw >= wmin) ? ~0ull : 0ull;
            u64 cur = __shfl(remv, c);   // word c of accumulated suppression
#pragma unroll
            for (int blk = 0; blk < 8; blk++) {
                u64 R[8], rwv[8];
#pragma unroll
                for (int k = 0; k < 8; k++)
                    R[k] = lb[(size_t)(blk * 8 + k) * MW + lw] & vmask;   // lane word
#pragma unroll
                for (int k = 0; k < 8; k++)
                    rwv[k] = lb[(size_t)(blk * 8 + k) * MW + c];      // broadcast word c
#pragma unroll
                for (int k = 0; k < 8; k++) {
                    const int p = blk * 8 + k;                        // compile-time
                    u64 msk = ((cur >> p) & 1ull) ? 0ull : ~0ull;
                    remv |= R[k] & msk;
                    cur  |= rwv[k] & msk;
                }
            }
            kept_total += 64 - (int)__popcll(cur);
            if (c + 1 < NCHUNK && kept_total >= KEEP_POST) {
                if (lw > c) remv = ~0ull;     // force-suppress unprocessed rows
                if (tid == 0) ls_stop = 1;
            }
        }
        __syncthreads();
        if (ls_stop) break;
    }

    if (tid < MW) {
        u64 kw = ~remv;
        if (tid == MW - 1) kw &= (1ull << (KEEP_PRE - 64 * (MW - 1))) - 1ull;
        keepw[tid] = kw;
    }
    __syncthreads();
    if (tid == 0) {
        u32 cnt = 0;
        for (int w = 0; w < MW; w++) { wpre[w] = cnt; cnt += (u32)__popcll(keepw[w]); }
        wpre[MW] = cnt;
    }
    __syncthreads();
    const int total = (int)wpre[MW];
    float* outb = out + (size_t)b * KEEP_POST * 5;
    for (int i = tid; i < KEEP_PRE; i += 256) {
        int w = i >> 6;
        u64 kw = keepw[w];
        if ((kw >> (i & 63)) & 1ull) {
            int rank = (int)wpre[w] + __popcll(kw & ((1ull << (i & 63)) - 1ull));
            if (rank < KEEP_POST) {
                float4 bx = selbox[(size_t)b * KEEP_PRE + i];
                float sc = selscore[(size_t)b * KEEP_PRE + i];
                outb[rank * 5 + 0] = bx.x;
                outb[rank * 5 + 1] = bx.y;
                outb[rank * 5 + 2] = bx.z;
                outb[rank * 5 + 3] = bx.w;
                outb[rank * 5 + 4] = sc;
            }
        }
    }
    for (int r = tid; r < KEEP_POST; r += 256) {
        if (r >= total) {
            outb[r * 5 + 0] = 0.0f;
            outb[r * 5 + 1] = 0.0f;
            outb[r * 5 + 2] = 0.0f;
            outb[r * 5 + 3] = 0.0f;
            outb[r * 5 + 4] = 0.0f;
        }
    }
}

extern "C" void kernel_launch(void* const* d_in, const int* in_sizes, int n_in,
                              void* d_out, int out_size, void* d_ws, size_t ws_size,
                              hipStream_t stream) {
    const float* logits  = (const float*)d_in[0];   // [32,90000,1]
    const float* deltas  = (const float*)d_in[1];   // [32,90000,4]
    const float* anchors = (const float*)d_in[2];   // [90000,4]
    const int* p_img_h   = (const int*)d_in[3];
    const int* p_img_w   = (const int*)d_in[4];

    char* ws = (char*)d_ws;
    u32* histg      = (u32*)(ws + HISTG_OFF);
    u32* Sg         = (u32*)(ws + SG_OFF);
    u64* grpg       = (u64*)(ws + GRP_OFF);
    float4* selbox  = (float4*)(ws + BOX_OFF);
    float* selscore = (float*)(ws + SCORE_OFF);
    u64* mask       = (u64*)(ws + MASK_OFF);

    // 5 nodes, all parallel-wide; no memset needed (exact-range compaction).
    hist8_kernel<<<dim3(NSL, BS), 1024, 0, stream>>>(logits, histg);
    compact8_kernel<<<dim3(NSL, BS), 1024, 0, stream>>>(logits, histg, Sg, grpg);
    rank_kernel<<<dim3(BS), 1024, 0, stream>>>(deltas, anchors, Sg, grpg,
                                               selbox, selscore, p_img_h, p_img_w);
    iou_kernel<<<dim3(40, BS), 256, 0, stream>>>(selbox, mask);
    nms_out_kernel<<<BS, 256, 0, stream>>>(mask, selbox, selscore, (float*)d_out);
}